// Round 5
// baseline (311.728 us; speedup 1.0000x reference)
//
#include <hip/hip_runtime.h>

// RandHashProj: out[b,o] = sum_{i: sel[i]==o} sign[i] * x[b,i]
// B=32, N=1e6, OUT_FEAT=1024. Memory-bound: 136 MB in, 128 KB out.
// Strategy: LDS accumulators (8 batch rows x 1024 feats = 32 KB/block),
// 4 batch-groups x 256 column-chunks grid, partials -> ws -> reduce.
// 32 KB LDS keeps 4 blocks/CU resident (32 waves/CU = max occupancy).
// Grid 4x256 = 1024 blocks = exactly 4/CU on 256 CUs.

constexpr int OUT_FEAT  = 1024;
constexpr int BGRP      = 8;                 // batch rows per block
constexpr int NGRP      = 4;                 // 32 / BGRP
constexpr int NCHUNK    = 256;               // column chunks
constexpr int BLK1      = 512;
constexpr int ACC_ELEMS = BGRP * OUT_FEAT;   // 8192 floats = 32 KB
constexpr int B_TOT     = 32;
constexpr int QUARTERS  = 4;
constexpr int CH_PER_Q  = NCHUNK / QUARTERS; // 64

__global__ __launch_bounds__(BLK1) void rhp_accum(
    const float* __restrict__ x, const int* __restrict__ sel,
    const float* __restrict__ sgn, float* __restrict__ ws,
    float* __restrict__ out_atomic, int N)
{
    __shared__ float acc[ACC_ELEMS];
    const int tid = threadIdx.x;
    for (int j = tid; j < ACC_ELEMS; j += BLK1) acc[j] = 0.0f;
    __syncthreads();

    const int g     = blockIdx.x;   // batch group 0..NGRP-1
    const int chunk = blockIdx.y;   // column chunk 0..NCHUNK-1
    const int b0    = g * BGRP;
    const int C4    = N >> 2;       // float4 columns (N divisible by 4)
    const int per   = (C4 + NCHUNK - 1) / NCHUNK;
    const int start = chunk * per;
    const int end   = min(start + per, C4);

    const float4* __restrict__ x4   = (const float4*)x;
    const int4*   __restrict__ sel4 = (const int4*)sel;
    const float4* __restrict__ sg4  = (const float4*)sgn;

    for (int c = start + tid; c < end; c += BLK1) {
        const int4   s  = sel4[c];
        const float4 sg = sg4[c];
        #pragma unroll
        for (int bb = 0; bb < BGRP; ++bb) {
            const float4 xv = x4[(size_t)(b0 + bb) * C4 + c];
            atomicAdd(&acc[bb * OUT_FEAT + s.x], xv.x * sg.x);
            atomicAdd(&acc[bb * OUT_FEAT + s.y], xv.y * sg.y);
            atomicAdd(&acc[bb * OUT_FEAT + s.z], xv.z * sg.z);
            atomicAdd(&acc[bb * OUT_FEAT + s.w], xv.w * sg.w);
        }
    }
    __syncthreads();

    if (ws) {
        // coalesced float4 flush of the 32 KB partial
        float4* dst = (float4*)(ws + (size_t)(g * NCHUNK + chunk) * ACC_ELEMS);
        const float4* srcv = (const float4*)acc;
        for (int j = tid; j < ACC_ELEMS / 4; j += BLK1) dst[j] = srcv[j];
    } else {
        // fallback: direct global atomic flush (out pre-zeroed)
        for (int j = tid; j < ACC_ELEMS; j += BLK1) {
            int bl = j >> 10, o = j & (OUT_FEAT - 1);
            atomicAdd(&out_atomic[(size_t)(b0 + bl) * OUT_FEAT + o], acc[j]);
        }
    }
}

// ws layout: [g (NGRP)][chunk (256)][bl (BGRP)][o (1024)] f32
// Each thread owns one (b,o) for a quarter of the chunk range; atomicAdd combine.
__global__ __launch_bounds__(256) void rhp_reduce(
    const float* __restrict__ ws, float* __restrict__ out)
{
    const int t = blockIdx.x * 256 + threadIdx.x;   // 0 .. 32*1024*4-1
    const int j = t & (B_TOT * OUT_FEAT - 1);       // output index 0..32767
    const int q = t >> 15;                          // chunk quarter 0..3
    const int b = j >> 10;                          // batch row 0..31
    const int o = j & (OUT_FEAT - 1);
    const int g  = b / BGRP;
    const int bl = b % BGRP;

    const float* src = ws + (size_t)g * NCHUNK * ACC_ELEMS
                          + (size_t)bl * OUT_FEAT + o;
    float acc = 0.0f;
    #pragma unroll 8
    for (int c = q * CH_PER_Q; c < (q + 1) * CH_PER_Q; ++c)
        acc += src[(size_t)c * ACC_ELEMS];
    atomicAdd(&out[j], acc);
}

extern "C" void kernel_launch(void* const* d_in, const int* in_sizes, int n_in,
                              void* d_out, int out_size, void* d_ws, size_t ws_size,
                              hipStream_t stream)
{
    const float* x   = (const float*)d_in[0];
    const int*   sel = (const int*)d_in[1];
    const float* sgn = (const float*)d_in[2];
    float*       out = (float*)d_out;
    const int    N   = in_sizes[1];              // 1,000,000

    const size_t need = (size_t)NGRP * NCHUNK * ACC_ELEMS * sizeof(float);

    // out is re-poisoned to 0xAA before every timed launch — zero it.
    hipMemsetAsync(d_out, 0, (size_t)out_size * sizeof(float), stream);

    if (ws_size >= need) {
        float* ws = (float*)d_ws;
        rhp_accum<<<dim3(NGRP, NCHUNK), BLK1, 0, stream>>>(x, sel, sgn, ws, nullptr, N);
        rhp_reduce<<<(B_TOT * OUT_FEAT * QUARTERS) / 256, 256, 0, stream>>>(ws, out);
    } else {
        rhp_accum<<<dim3(NGRP, NCHUNK), BLK1, 0, stream>>>(x, sel, sgn, nullptr, out, N);
    }
}